// Round 5
// baseline (338.003 us; speedup 1.0000x reference)
//
#include <hip/hip_runtime.h>
#include <hip/hip_bf16.h>
#include <stdint.h>

// SymmetricTensorProduct: n=8192, MUL=128, DIM_IN=512
//   out_s[z,u] = (1/16)*xs[z,u]*S[z,u] + (1/(16*sqrt3))*sum_i V_i[z,u]*xv[z,u,i]
//   t[z,v,w]   = sum_u xs[z,u]*w_sv[u,v,w]
//   out_v[z,w,i] = (1/128)*sum_v t[z,v,w]*xv[z,v,i]
//
// Round-5 outv: T3/T4 schedule. Block=512thr (8 waves = 2zg x 2wg x 2vg),
// tile 128z x 32w x all v; macro = 4 v per barrier, A dbuf 2x32KB staged via
// global_load_lds, counted vmcnt(28) (never 0 in loop), raw s_barrier.
// vg splits v 2+2 per macro (halves LDS-read redundancy); vg-pair summed via
// LDS at the end. xv via direct uint loads from xvq[i][z][v] (bf16 pair).

#define NZ 8192
#define NM (8192*128)

typedef __attribute__((ext_vector_type(8))) short bf16x8;
typedef __attribute__((ext_vector_type(4))) float f32x4;

__device__ __forceinline__ ushort f2bf(float f) {
  uint32_t u = __builtin_bit_cast(uint32_t, f);
  u += 0x7fffu + ((u >> 16) & 1u);   // RNE
  return (ushort)(u >> 16);
}
__device__ __forceinline__ void gload16(const void* g, void* l) {
  __builtin_amdgcn_global_load_lds((const __attribute__((address_space(1))) void*)g,
                                   (__attribute__((address_space(3))) void*)l, 16, 0, 0);
}

// ---------------- prep: xs_bf, xvq planes, w casts --------------------------
__global__ void prep_cast(const float* __restrict__ x,
                          const float* __restrict__ w_ss,
                          const float* __restrict__ w_vv,
                          ushort* __restrict__ xs_bf,
                          ushort* __restrict__ xvq,
                          ushort* __restrict__ wssb,
                          ushort* __restrict__ wvvb) {
  int bid = blockIdx.x, tid = threadIdx.x;
  if (bid < 4096) {
    int z = bid * 2 + (tid >> 7), v = tid & 127;
    const float* xr = x + (size_t)z * 512;
    xs_bf[z * 128 + v] = f2bf(xr[v]);
#pragma unroll
    for (int i = 0; i < 3; ++i)
      xvq[((size_t)i * NZ + z) * 128 + v] = f2bf(xr[128 + 3 * v + i]);
  } else {
    int k = (bid - 4096) * 256 + tid;
    if (k < 16384) wssb[k] = f2bf(w_ss[k]);
    else wvvb[k - 16384] = f2bf(w_vv[k - 16384]);
  }
}

// ---- prep: transpose w_sv[u][v][w] -> Wt[(v,w)][k^((m&7)<<3)] (bf16) ------
__global__ void prep_transpose(const float* __restrict__ w_sv,
                               ushort* __restrict__ Wt) {
  __shared__ float tile[32][129];
  int bu = blockIdx.x & 3;
  int bm = blockIdx.x >> 2;
  int t = threadIdx.x;
  int u0 = bu * 32, m0 = bm * 128;
  for (int rr = 0; rr < 32; rr += 2) {
    int u = u0 + rr + (t >> 7);
    int m = m0 + (t & 127);
    tile[rr + (t >> 7)][t & 127] = w_sv[(size_t)u * 16384 + m];
  }
  __syncthreads();
  for (int mm = 0; mm < 128; mm += 8) {
    int m = m0 + mm + (t >> 5);
    int k = u0 + (t & 31);
    Wt[(size_t)m * 128 + (k ^ ((m & 7) << 3))] = f2bf(tile[t & 31][mm + (t >> 5)]);
  }
}

// ---------------- out_s via MFMA (x read once per block) --------------------
__global__ __launch_bounds__(128) void outs_mfma(
    const float* __restrict__ x, const ushort* __restrict__ xs_bf,
    const ushort* __restrict__ wssb, const ushort* __restrict__ wvvb,
    float* __restrict__ out) {
  int tid = threadIdx.x, wid = tid >> 6, l = tid & 63;
  int lr = l & 15, lg = l >> 4;
  int z = blockIdx.x * 32 + wid * 16 + lr;
  const float* xrow = x + (size_t)z * 512;

  bf16x8 bs[4], b0[4], b1[4], b2[4];
#pragma unroll
  for (int kk = 0; kk < 4; ++kk) {
    int k0 = kk * 32 + lg * 8;
    bs[kk] = *(const bf16x8*)(xs_bf + (size_t)z * 128 + k0);
    float4 f[6];
    const float4* src = (const float4*)(xrow + 128 + 3 * k0);
#pragma unroll
    for (int q = 0; q < 6; ++q) f[q] = src[q];
    const float* ff = (const float*)f;
#pragma unroll
    for (int jj = 0; jj < 8; ++jj) {
      b0[kk][jj] = (short)f2bf(ff[3 * jj + 0]);
      b1[kk][jj] = (short)f2bf(ff[3 * jj + 1]);
      b2[kk][jj] = (short)f2bf(ff[3 * jj + 2]);
    }
  }
#pragma unroll 2
  for (int ut = 0; ut < 8; ++ut) {
    int u0 = ut * 16;
    f32x4 css = {0.f, 0.f, 0.f, 0.f};
    f32x4 cv0 = {0.f, 0.f, 0.f, 0.f};
    f32x4 cv1 = {0.f, 0.f, 0.f, 0.f};
    f32x4 cv2 = {0.f, 0.f, 0.f, 0.f};
#pragma unroll
    for (int kk = 0; kk < 4; ++kk) {
      int k0 = kk * 32 + lg * 8;
      bf16x8 as = *(const bf16x8*)(wssb + (size_t)(u0 + lr) * 128 + k0);
      bf16x8 av = *(const bf16x8*)(wvvb + (size_t)(u0 + lr) * 128 + k0);
      css = __builtin_amdgcn_mfma_f32_16x16x32_bf16(as, bs[kk], css, 0, 0, 0);
      cv0 = __builtin_amdgcn_mfma_f32_16x16x32_bf16(av, b0[kk], cv0, 0, 0, 0);
      cv1 = __builtin_amdgcn_mfma_f32_16x16x32_bf16(av, b1[kk], cv1, 0, 0, 0);
      cv2 = __builtin_amdgcn_mfma_f32_16x16x32_bf16(av, b2[kk], cv2, 0, 0, 0);
    }
#pragma unroll
    for (int r = 0; r < 4; ++r) {
      int u = u0 + lg * 4 + r;
      float xsv = xrow[u];
      const float* xvu = xrow + 128 + 3 * u;
      out[(size_t)z * 512 + u] =
          0.0625f * xsv * css[r] +
          0.036084391824351615f * (cv0[r] * xvu[0] + cv1[r] * xvu[1] + cv2[r] * xvu[2]);
    }
  }
}

// ---------------- out_v -----------------------------------------------------
// grid 256 = 64 zb(128z) x 4 wc(32w, XCD-pinned). 8 waves: vg=wid&1,
// wg=(wid>>1)&1, zg=wid>>2. Wave: 64z (4 n-tiles) x 16w x (2 of 4 v)/macro.
#define OUTV_BODY(T, XU, DOXD, XUN)                                            \
  {                                                                            \
    const int cbT = (T) & 1;                                                   \
    const char* ab = lds + cbT * 32768;                                        \
    _Pragma("unroll")                                                          \
    for (int j = 0; j < 2; ++j) {                                              \
      const char* rowp = ab + (2 * vg + j) * 8192 + rowoff;                    \
      bf16x8 a0 = *(const bf16x8*)(rowp + fk0);                                \
      bf16x8 a1 = *(const bf16x8*)(rowp + fk1);                                \
      bf16x8 a2 = *(const bf16x8*)(rowp + fk2);                                \
      bf16x8 a3 = *(const bf16x8*)(rowp + fk3);                                \
      _Pragma("unroll")                                                        \
      for (int n = 0; n < 4; ++n) {                                            \
        f32x4 tt = {0.f, 0.f, 0.f, 0.f};                                       \
        __builtin_amdgcn_s_setprio(1);                                         \
        tt = __builtin_amdgcn_mfma_f32_16x16x32_bf16(a0, b[n][0], tt, 0, 0, 0);\
        tt = __builtin_amdgcn_mfma_f32_16x16x32_bf16(a1, b[n][1], tt, 0, 0, 0);\
        tt = __builtin_amdgcn_mfma_f32_16x16x32_bf16(a2, b[n][2], tt, 0, 0, 0);\
        tt = __builtin_amdgcn_mfma_f32_16x16x32_bf16(a3, b[n][3], tt, 0, 0, 0);\
        __builtin_amdgcn_s_setprio(0);                                         \
        uint u0w = XU[(0 * 4 + n) * 2 + ((T) & 1)];                            \
        uint u1w = XU[(1 * 4 + n) * 2 + ((T) & 1)];                            \
        uint u2w = XU[(2 * 4 + n) * 2 + ((T) & 1)];                            \
        float x0, x1, x2;                                                      \
        if (j == 0) {                                                          \
          x0 = __builtin_bit_cast(float, u0w << 16);                           \
          x1 = __builtin_bit_cast(float, u1w << 16);                           \
          x2 = __builtin_bit_cast(float, u2w << 16);                           \
        } else {                                                               \
          x0 = __builtin_bit_cast(float, u0w & 0xffff0000u);                   \
          x1 = __builtin_bit_cast(float, u1w & 0xffff0000u);                   \
          x2 = __builtin_bit_cast(float, u2w & 0xffff0000u);                   \
        }                                                                      \
        _Pragma("unroll")                                                      \
        for (int r = 0; r < 4; ++r) {                                          \
          acc[n][r][0] += tt[r] * x0;                                          \
          acc[n][r][1] += tt[r] * x1;                                          \
          acc[n][r][2] += tt[r] * x2;                                          \
        }                                                                      \
      }                                                                        \
    }                                                                          \
    asm volatile("s_waitcnt lgkmcnt(0)" ::: "memory");                         \
    __builtin_amdgcn_sched_barrier(0);                                         \
    __builtin_amdgcn_s_barrier();                                              \
    if ((T) < 30) {                                                            \
      _Pragma("unroll")                                                        \
      for (int r5 = 0; r5 < 4; ++r5)                                           \
        gload16(Wt + (((size_t)((T) + 2) * 4 + r5) * 128 + wc * 32) * 128 +    \
                    tid * 8,                                                   \
                lds + cbT * 32768 + r5 * 8192 + wid * 1024);                   \
    }                                                                          \
    if (DOXD && (T) < 30) {                                                    \
      _Pragma("unroll")                                                        \
      for (int i2 = 0; i2 < 3; ++i2)                                           \
        _Pragma("unroll")                                                      \
        for (int n2 = 0; n2 < 4; ++n2)                                         \
          _Pragma("unroll")                                                    \
          for (int p2 = 0; p2 < 2; ++p2)                                       \
            XUN[(i2 * 4 + n2) * 2 + p2] = *(const uint*)(                      \
                xvq + ((size_t)i2 * NZ + zbase + n2 * 16) * 128 +              \
                ((T) + 2) * 4 + p2 * 4 + 2 * vg);                              \
    }                                                                          \
    if ((T) < 30)                                                              \
      asm volatile("s_waitcnt vmcnt(28)" ::: "memory");                        \
    else if ((T) == 30)                                                        \
      asm volatile("s_waitcnt vmcnt(0)" ::: "memory");                         \
    __builtin_amdgcn_sched_barrier(0);                                         \
  }

__global__ __launch_bounds__(512, 2) void outv_kernel(
    const ushort* __restrict__ xs_bf, const ushort* __restrict__ xvq,
    const ushort* __restrict__ Wt, float* __restrict__ out) {
  __shared__ char lds[65536];
  int bid = blockIdx.x;
  int wc = bid & 3, zb = bid >> 2;
  int tid = threadIdx.x;
  int wid = tid >> 6, l = tid & 63;
  int vg = wid & 1, wg = (wid >> 1) & 1, zg = wid >> 2;
  int lr = l & 15, lg = l >> 4;

  int zbase = zb * 128 + zg * 64 + lr;      // + n*16
  int rowoff = (wg * 16 + lr) * 256;
  int sw = (lr & 7) << 3;
  int fk0 = 2 * ((0 * 32 + lg * 8) ^ sw);
  int fk1 = 2 * ((1 * 32 + lg * 8) ^ sw);
  int fk2 = 2 * ((2 * 32 + lg * 8) ^ sw);
  int fk3 = 2 * ((3 * 32 + lg * 8) ^ sw);

  // B-fragments (xs), held all kernel: 4 n-tiles x 4 k-chunks
  bf16x8 b[4][4];
#pragma unroll
  for (int n = 0; n < 4; ++n)
#pragma unroll
    for (int kk = 0; kk < 4; ++kk)
      b[n][kk] = *(const bf16x8*)(xs_bf + (size_t)(zbase + n * 16) * 128 + kk * 32 + lg * 8);

  // xv pair-loads for macros {0,1}
  uint xu0[24], xu1[24];
#pragma unroll
  for (int i = 0; i < 3; ++i)
#pragma unroll
    for (int n = 0; n < 4; ++n)
#pragma unroll
      for (int p = 0; p < 2; ++p)
        xu0[(i * 4 + n) * 2 + p] =
            *(const uint*)(xvq + ((size_t)i * NZ + zbase + n * 16) * 128 + p * 4 + 2 * vg);

  // stage macros 0 (buf0) and 1 (buf1)
#pragma unroll
  for (int r5 = 0; r5 < 4; ++r5)
    gload16(Wt + ((size_t)r5 * 128 + wc * 32) * 128 + tid * 8,
            lds + r5 * 8192 + wid * 1024);
#pragma unroll
  for (int r5 = 0; r5 < 4; ++r5)
    gload16(Wt + ((size_t)(4 + r5) * 128 + wc * 32) * 128 + tid * 8,
            lds + 32768 + r5 * 8192 + wid * 1024);

  asm volatile("s_waitcnt vmcnt(4)" ::: "memory");
  __builtin_amdgcn_sched_barrier(0);
  __builtin_amdgcn_s_barrier();

  float acc[4][4][3] = {};

  for (int q = 0; q < 8; ++q) {
    OUTV_BODY(4 * q + 0, xu0, 1, xu1);
    OUTV_BODY(4 * q + 1, xu0, 0, xu1);
    OUTV_BODY(4 * q + 2, xu1, 1, xu0);
    OUTV_BODY(4 * q + 3, xu1, 0, xu0);
  }

  // combine vg halves via LDS (reuse A buffer; all reads done after last BAR)
  float* red = (float*)lds;
  int rrow = (zg * 2 + wg) * 64 + l;
  if (vg == 1) {
#pragma unroll
    for (int n = 0; n < 4; ++n)
#pragma unroll
      for (int r = 0; r < 4; ++r)
#pragma unroll
        for (int i = 0; i < 3; ++i)
          red[rrow * 49 + n * 12 + r * 3 + i] = acc[n][r][i];
  }
  __builtin_amdgcn_s_barrier();
  if (vg == 0) {
#pragma unroll
    for (int n = 0; n < 4; ++n) {
#pragma unroll
      for (int r = 0; r < 4; ++r) {
        int z = zbase + n * 16;
        int w = wc * 32 + wg * 16 + lg * 4 + r;
        float* o = out + (size_t)z * 512 + 128 + 3 * w;
        o[0] = (acc[n][r][0] + red[rrow * 49 + n * 12 + r * 3 + 0]) * 0.0078125f;
        o[1] = (acc[n][r][1] + red[rrow * 49 + n * 12 + r * 3 + 1]) * 0.0078125f;
        o[2] = (acc[n][r][2] + red[rrow * 49 + n * 12 + r * 3 + 2]) * 0.0078125f;
      }
    }
  }
}

// ---------------- launch ----------------------------------------------------
extern "C" void kernel_launch(void* const* d_in, const int* in_sizes, int n_in,
                              void* d_out, int out_size, void* d_ws, size_t ws_size,
                              hipStream_t stream) {
  const float* x    = (const float*)d_in[0];
  const float* w_ss = (const float*)d_in[1];
  const float* w_sv = (const float*)d_in[2];
  const float* w_vv = (const float*)d_in[3];
  float* out = (float*)d_out;

  char* ws = (char*)d_ws;
  ushort* xs_bf = (ushort*)ws;                                  // 2 MB
  ushort* Wt    = (ushort*)(ws + (size_t)2 * 1024 * 1024);      // 4 MB (swizzled)
  ushort* xvq   = (ushort*)(ws + (size_t)6 * 1024 * 1024);      // 6 MB
  ushort* wssb  = (ushort*)(ws + (size_t)12 * 1024 * 1024);     // 32 KB
  ushort* wvvb  = (ushort*)(ws + (size_t)12 * 1024 * 1024 + 32768);

  prep_cast<<<4224, 256, 0, stream>>>(x, w_ss, w_vv, xs_bf, xvq, wssb, wvvb);
  prep_transpose<<<512, 256, 0, stream>>>(w_sv, Wt);
  outs_mfma<<<256, 128, 0, stream>>>(x, xs_bf, wssb, wvvb, out);
  outv_kernel<<<256, 512, 0, stream>>>(xs_bf, xvq, Wt, out);
}

// Round 6
// 100.972 us; speedup vs baseline: 3.3475x; 3.3475x over previous
//
#include <hip/hip_runtime.h>
#include <hip/hip_bf16.h>
#include <stdint.h>

// SymmetricTensorProduct: n=8192, MUL=128, DIM_IN=512
//   out_s[z,u] = (1/16)*xs[z,u]*S[z,u] + (1/(16*sqrt3))*sum_i V_i[z,u]*xv[z,u,i]
//   t[z,v,w]   = sum_u xs[z,u]*w_sv[u,v,w]
//   out_v[z,w,i] = (1/128)*sum_v t[z,v,w]*xv[z,v,i]
//
// Round-6 outv: 8 waves (4zg x 2wg), tile 128z x 32w, all 128 v.
// Wt pre-arranged in FRAGMENT ORDER [v][wc][wg][kk][lane][8] so staging is one
// linear gload16 per thread and every ds_read_b128 is lane-consecutive
// (conflict-free by construction). 4-buffer LDS (32KB), depth-2 prefetch,
// counted s_waitcnt vmcnt(7), raw s_barrier, issues pinned by sched_barrier.

#define NZ 8192
#define NM (8192*128)

typedef __attribute__((ext_vector_type(8))) short bf16x8;
typedef __attribute__((ext_vector_type(4))) float f32x4;

__device__ __forceinline__ ushort f2bf(float f) {
  uint32_t u = __builtin_bit_cast(uint32_t, f);
  u += 0x7fffu + ((u >> 16) & 1u);   // RNE
  return (ushort)(u >> 16);
}
__device__ __forceinline__ float bf2f(ushort u) {
  uint32_t v = ((uint32_t)u) << 16;
  return __builtin_bit_cast(float, v);
}
__device__ __forceinline__ void gload16(const void* g, void* l) {
  __builtin_amdgcn_global_load_lds((const __attribute__((address_space(1))) void*)g,
                                   (__attribute__((address_space(3))) void*)l, 16, 0, 0);
}

// ---------------- prep: xs_bf + xvp planes (LDS transpose) + w casts --------
__global__ __launch_bounds__(256) void prep_cast(
    const float* __restrict__ x, const float* __restrict__ w_ss,
    const float* __restrict__ w_vv, ushort* __restrict__ xs_bf,
    ushort* __restrict__ xvp, ushort* __restrict__ wssb,
    ushort* __restrict__ wvvb) {
  int bid = blockIdx.x, tid = threadIdx.x;
  if (bid < 128) {
    __shared__ ushort tile[3 * 128 * 64];   // [i][v][zloc]
    int z0 = bid * 64;
#pragma unroll 4
    for (int it = 0; it < 32; ++it) {
      int idx = it * 256 + tid;             // 0..8191
      int zloc = idx >> 7, c4 = idx & 127;
      float4 f = *(const float4*)(x + (size_t)(z0 + zloc) * 512 + c4 * 4);
      if (c4 < 32) {
        ushort4 o;
        o.x = f2bf(f.x); o.y = f2bf(f.y); o.z = f2bf(f.z); o.w = f2bf(f.w);
        *(ushort4*)(xs_bf + (size_t)(z0 + zloc) * 128 + c4 * 4) = o;
      } else {
        int c = c4 * 4 - 128;               // 0..383
        float vals[4] = {f.x, f.y, f.z, f.w};
#pragma unroll
        for (int e = 0; e < 4; ++e) {
          int cc = c + e, v = cc / 3, i = cc - 3 * v;
          tile[i * 8192 + v * 64 + zloc] = f2bf(vals[e]);
        }
      }
    }
    __syncthreads();
#pragma unroll
    for (int it = 0; it < 12; ++it) {
      int idx = it * 256 + tid;             // 0..3071
      int row = idx >> 3, p = idx & 7;
      int i = row >> 7, v = row & 127;
      *(bf16x8*)(xvp + (size_t)i * NM + (size_t)v * 8192 + z0 + p * 8) =
          *(const bf16x8*)(tile + i * 8192 + v * 64 + p * 8);
    }
  } else {
    int k = (bid - 128) * 256 + tid;
    if (k < 16384) wssb[k] = f2bf(w_ss[k]);
    else wvvb[k - 16384] = f2bf(w_vv[k - 16384]);
  }
}

// ---- prep: w_sv[u][v][w] -> Wt fragment order [v][wc][wg][kk][l][e] --------
__global__ __launch_bounds__(256) void prep_wt(const float* __restrict__ w_sv,
                                               ushort* __restrict__ Wt) {
  __shared__ ushort tile[4096];
  int v = blockIdx.x >> 2, wc = blockIdx.x & 3;
  int t = threadIdx.x;
  int u = t >> 1, wh = t & 1;
  const float* src = w_sv + (size_t)u * 16384 + v * 128 + wc * 32 + wh * 16;
  int kk = u >> 5, lg = (u >> 3) & 3, e = u & 7;
#pragma unroll
  for (int ww = 0; ww < 16; ++ww)
    tile[wh * 2048 + kk * 512 + (lg * 16 + ww) * 8 + e] = f2bf(src[ww]);
  __syncthreads();
  bf16x8* dst = (bf16x8*)(Wt + ((size_t)v * 4 + wc) * 4096);
  const bf16x8* s = (const bf16x8*)tile;
  dst[t] = s[t];
  dst[t + 256] = s[t + 256];
}

// ---------------- out_s via MFMA --------------------------------------------
__global__ __launch_bounds__(128) void outs_mfma(
    const float* __restrict__ x, const ushort* __restrict__ xs_bf,
    const ushort* __restrict__ wssb, const ushort* __restrict__ wvvb,
    float* __restrict__ out) {
  int tid = threadIdx.x, wid = tid >> 6, l = tid & 63;
  int lr = l & 15, lg = l >> 4;
  int z = blockIdx.x * 32 + wid * 16 + lr;
  const float* xrow = x + (size_t)z * 512;

  bf16x8 bs[4], b0[4], b1[4], b2[4];
#pragma unroll
  for (int kk = 0; kk < 4; ++kk) {
    int k0 = kk * 32 + lg * 8;
    bs[kk] = *(const bf16x8*)(xs_bf + (size_t)z * 128 + k0);
    float4 f[6];
    const float4* src = (const float4*)(xrow + 128 + 3 * k0);
#pragma unroll
    for (int q = 0; q < 6; ++q) f[q] = src[q];
    const float* ff = (const float*)f;
#pragma unroll
    for (int jj = 0; jj < 8; ++jj) {
      b0[kk][jj] = (short)f2bf(ff[3 * jj + 0]);
      b1[kk][jj] = (short)f2bf(ff[3 * jj + 1]);
      b2[kk][jj] = (short)f2bf(ff[3 * jj + 2]);
    }
  }
#pragma unroll 2
  for (int ut = 0; ut < 8; ++ut) {
    int u0 = ut * 16;
    f32x4 css = {0.f, 0.f, 0.f, 0.f};
    f32x4 cv0 = {0.f, 0.f, 0.f, 0.f};
    f32x4 cv1 = {0.f, 0.f, 0.f, 0.f};
    f32x4 cv2 = {0.f, 0.f, 0.f, 0.f};
#pragma unroll
    for (int kk = 0; kk < 4; ++kk) {
      int k0 = kk * 32 + lg * 8;
      bf16x8 as = *(const bf16x8*)(wssb + (size_t)(u0 + lr) * 128 + k0);
      bf16x8 av = *(const bf16x8*)(wvvb + (size_t)(u0 + lr) * 128 + k0);
      css = __builtin_amdgcn_mfma_f32_16x16x32_bf16(as, bs[kk], css, 0, 0, 0);
      cv0 = __builtin_amdgcn_mfma_f32_16x16x32_bf16(av, b0[kk], cv0, 0, 0, 0);
      cv1 = __builtin_amdgcn_mfma_f32_16x16x32_bf16(av, b1[kk], cv1, 0, 0, 0);
      cv2 = __builtin_amdgcn_mfma_f32_16x16x32_bf16(av, b2[kk], cv2, 0, 0, 0);
    }
#pragma unroll
    for (int r = 0; r < 4; ++r) {
      int u = u0 + lg * 4 + r;
      float xsv = xrow[u];
      const float* xvu = xrow + 128 + 3 * u;
      out[(size_t)z * 512 + u] =
          0.0625f * xsv * css[r] +
          0.036084391824351615f * (cv0[r] * xvu[0] + cv1[r] * xvu[1] + cv2[r] * xvu[2]);
    }
  }
}

// ---------------- out_v -----------------------------------------------------
// grid 256 = 64 zb(128z) x 4 wc(32w); 1 block/CU. 8 waves: wg=wid&1, zg=wid>>1.
// Wave: 32z (2 n-tiles) x 16w x all v. Per phase (1 v): 1 gload16 + 6 xv loads,
// 4 ds_read_b128, 8 MFMA, 24 FMA; vmcnt(7) counted; 4-deep LDS rotation.

#define OUTV_PHASE(V, CUR, NXT, SC, SN)                                        \
  do {                                                                         \
    asm volatile("s_waitcnt vmcnt(7)" ::: "memory");                           \
    __builtin_amdgcn_s_barrier();                                              \
    __builtin_amdgcn_sched_barrier(0);                                         \
    int vs = (V) + 2; if (vs > 127) vs = 127;                                  \
    gload16(Wt + ((size_t)vs * 4 + wc) * 4096 + tid * 8,                       \
            lds + (NXT) * 8192 + tid * 16);                                    \
    const ushort* xq = xvp + (size_t)vs * 8192 + z0;                           \
    SN[0] = xq[0];        SN[1] = xq[16];                                      \
    SN[2] = xq[NM];       SN[3] = xq[NM + 16];                                 \
    SN[4] = xq[2 * NM];   SN[5] = xq[2 * NM + 16];                             \
    __builtin_amdgcn_sched_barrier(0);                                         \
    const char* ab = lds + (CUR) * 8192 + wg * 4096 + l * 16;                  \
    bf16x8 a0 = *(const bf16x8*)(ab);                                          \
    bf16x8 a1 = *(const bf16x8*)(ab + 1024);                                   \
    bf16x8 a2 = *(const bf16x8*)(ab + 2048);                                   \
    bf16x8 a3 = *(const bf16x8*)(ab + 3072);                                   \
    _Pragma("unroll")                                                          \
    for (int n = 0; n < 2; ++n) {                                              \
      f32x4 tt = {0.f, 0.f, 0.f, 0.f};                                         \
      __builtin_amdgcn_s_setprio(1);                                           \
      tt = __builtin_amdgcn_mfma_f32_16x16x32_bf16(a0, b[n][0], tt, 0, 0, 0);  \
      tt = __builtin_amdgcn_mfma_f32_16x16x32_bf16(a1, b[n][1], tt, 0, 0, 0);  \
      tt = __builtin_amdgcn_mfma_f32_16x16x32_bf16(a2, b[n][2], tt, 0, 0, 0);  \
      tt = __builtin_amdgcn_mfma_f32_16x16x32_bf16(a3, b[n][3], tt, 0, 0, 0);  \
      __builtin_amdgcn_s_setprio(0);                                           \
      float x0 = bf2f(SC[0 + n]);                                              \
      float x1 = bf2f(SC[2 + n]);                                              \
      float x2 = bf2f(SC[4 + n]);                                              \
      _Pragma("unroll")                                                        \
      for (int r = 0; r < 4; ++r) {                                            \
        acc[n][r][0] += tt[r] * x0;                                            \
        acc[n][r][1] += tt[r] * x1;                                            \
        acc[n][r][2] += tt[r] * x2;                                            \
      }                                                                        \
    }                                                                          \
  } while (0)

__global__ __launch_bounds__(512, 1) void outv_kernel(
    const ushort* __restrict__ xs_bf, const ushort* __restrict__ xvp,
    const ushort* __restrict__ Wt, float* __restrict__ out) {
  __shared__ char lds[32768];
  int bid = blockIdx.x;
  int wc = bid & 3, zb = bid >> 2;
  int tid = threadIdx.x;
  int wid = tid >> 6, l = tid & 63;
  int wg = wid & 1, zg = wid >> 1;
  int lr = l & 15, lg = l >> 4;
  int z0 = zb * 128 + zg * 32 + lr;        // n-tile adds 16
  int w0 = wc * 32 + wg * 16;

  // B-fragments (xs), held all kernel: 2 n-tiles x 4 k-chunks
  bf16x8 b[2][4];
#pragma unroll
  for (int n = 0; n < 2; ++n)
#pragma unroll
    for (int kk = 0; kk < 4; ++kk)
      b[n][kk] = *(const bf16x8*)(xs_bf + (size_t)(z0 + n * 16) * 128 + kk * 32 + lg * 8);
  __builtin_amdgcn_sched_barrier(0);

  ushort s0[6], s1[6], s2[6], s3[6];
  // prologue: A(0)->buf0, xv(0)->s0, A(1)->buf1, xv(1)->s1  (14 vmem ops)
  {
    gload16(Wt + ((size_t)0 * 4 + wc) * 4096 + tid * 8, lds + tid * 16);
    const ushort* xq = xvp + z0;
    s0[0] = xq[0];      s0[1] = xq[16];
    s0[2] = xq[NM];     s0[3] = xq[NM + 16];
    s0[4] = xq[2 * NM]; s0[5] = xq[2 * NM + 16];
    __builtin_amdgcn_sched_barrier(0);
    gload16(Wt + ((size_t)1 * 4 + wc) * 4096 + tid * 8, lds + 8192 + tid * 16);
    xq = xvp + 8192 + z0;
    s1[0] = xq[0];      s1[1] = xq[16];
    s1[2] = xq[NM];     s1[3] = xq[NM + 16];
    s1[4] = xq[2 * NM]; s1[5] = xq[2 * NM + 16];
    __builtin_amdgcn_sched_barrier(0);
  }

  float acc[2][4][3] = {};

  for (int q = 0; q < 32; ++q) {
    int v = q * 4;
    OUTV_PHASE(v + 0, 0, 2, s0, s2);
    OUTV_PHASE(v + 1, 1, 3, s1, s3);
    OUTV_PHASE(v + 2, 2, 0, s2, s0);
    OUTV_PHASE(v + 3, 3, 1, s3, s1);
  }

#pragma unroll
  for (int n = 0; n < 2; ++n) {
#pragma unroll
    for (int r = 0; r < 4; ++r) {
      int z = z0 + n * 16;
      int w = w0 + lg * 4 + r;
      float* o = out + (size_t)z * 512 + 128 + 3 * w;
      o[0] = acc[n][r][0] * 0.0078125f;
      o[1] = acc[n][r][1] * 0.0078125f;
      o[2] = acc[n][r][2] * 0.0078125f;
    }
  }
}

// ---------------- launch ----------------------------------------------------
extern "C" void kernel_launch(void* const* d_in, const int* in_sizes, int n_in,
                              void* d_out, int out_size, void* d_ws, size_t ws_size,
                              hipStream_t stream) {
  const float* x    = (const float*)d_in[0];
  const float* w_ss = (const float*)d_in[1];
  const float* w_sv = (const float*)d_in[2];
  const float* w_vv = (const float*)d_in[3];
  float* out = (float*)d_out;

  char* ws = (char*)d_ws;
  ushort* xs_bf = (ushort*)ws;                                  // 2 MB
  ushort* Wt    = (ushort*)(ws + (size_t)2 * 1024 * 1024);      // 4 MB (frag order)
  ushort* xvp   = (ushort*)(ws + (size_t)6 * 1024 * 1024);      // 6 MB
  ushort* wssb  = (ushort*)(ws + (size_t)12 * 1024 * 1024);     // 32 KB
  ushort* wvvb  = (ushort*)(ws + (size_t)12 * 1024 * 1024 + 32768);

  prep_cast<<<256, 256, 0, stream>>>(x, w_ss, w_vv, xs_bf, xvp, wssb, wvvb);
  prep_wt<<<512, 256, 0, stream>>>(w_sv, Wt);
  outs_mfma<<<256, 128, 0, stream>>>(x, xs_bf, wssb, wvvb, out);
  outv_kernel<<<256, 512, 0, stream>>>(xs_bf, xvp, Wt, out);
}